// Round 15
// baseline (304.336 us; speedup 1.0000x reference)
//
#include <hip/hip_runtime.h>

#define N_NODES 100000
#define N_EDGES 1600000
#define H 128

#define NB 391        // dst buckets of 256 nodes: ceil(100000/256)
#define P1_EPB 4096   // edges per pass-1/bucket-count block
#define P1_BLOCKS ((N_EDGES + P1_EPB - 1) / P1_EPB)   // 391
#define P2_CAP 6144   // bucket capacity (mean 4096, sigma~64)

typedef unsigned short u16;
typedef unsigned int u32;
typedef short bf16x8 __attribute__((ext_vector_type(8)));
typedef float f32x4 __attribute__((ext_vector_type(4)));

static __device__ __forceinline__ u16 f2bf(float f) {  // RNE float->bf16
    u32 u = __float_as_uint(f);
    u += 0x7fffu + ((u >> 16) & 1u);
    return (u16)(u >> 16);
}

// ---------------- CSR build ----------------
// R12 lesson: per-node random global atomics cost ~32B HBM writeback each.
// All per-node counting happens in LDS inside the bucketed counting sort.

__global__ void zero_ints(int* __restrict__ p, int n) {
    int i = blockIdx.x * blockDim.x + threadIdx.x;
    if (i < n) p[i] = 0;
}

__global__ __launch_bounds__(1024) void bucket_count(
    const int* __restrict__ dst, int* __restrict__ gcount)
{
    __shared__ int s_cnt[NB];
    const int t = threadIdx.x;
    const int e0 = blockIdx.x * P1_EPB;
    const int ecnt = min(P1_EPB, N_EDGES - e0);
    for (int i = t; i < NB; i += 1024) s_cnt[i] = 0;
    __syncthreads();
    for (int i = t; i < ecnt; i += 1024)
        atomicAdd(&s_cnt[dst[e0 + i] >> 8], 1);
    __syncthreads();
    for (int i = t; i < NB; i += 1024)
        if (s_cnt[i] > 0) atomicAdd(&gcount[i], s_cnt[i]);
}

__global__ __launch_bounds__(512) void bucket_scan(
    const int* __restrict__ gcount, int* __restrict__ bstart, int* __restrict__ bcur)
{
    __shared__ int s[512];
    int t = threadIdx.x;
    int v = (t < NB) ? gcount[t] : 0;
    s[t] = v;
    __syncthreads();
    for (int off = 1; off < 512; off <<= 1) {
        int add = (t >= off) ? s[t - off] : 0;
        __syncthreads();
        s[t] += add;
        __syncthreads();
    }
    if (t < NB) {
        int excl = s[t] - v;
        bstart[t] = excl;
        bcur[t] = excl;
    }
    if (t == NB - 1) bstart[NB] = s[t];   // == N_EDGES
}

__global__ __launch_bounds__(1024) void p1_bin(
    const int* __restrict__ src, const int* __restrict__ dst,
    int* __restrict__ bcur, u32* __restrict__ csrp)
{
    __shared__ int s_cnt[NB];      // histogram, then running local cursor
    __shared__ int s_lstart[NB];
    __shared__ int s_gbase[NB];
    __shared__ int s_scan[512];
    __shared__ u32 s_val[P1_EPB];
    __shared__ u32 s_gaddr[P1_EPB];

    const int t = threadIdx.x;
    const int e0 = blockIdx.x * P1_EPB;
    const int ecnt = min(P1_EPB, N_EDGES - e0);

    for (int i = t; i < NB; i += 1024) s_cnt[i] = 0;
    __syncthreads();
    for (int i = t; i < ecnt; i += 1024)
        atomicAdd(&s_cnt[dst[e0 + i] >> 8], 1);
    __syncthreads();

    int v = (t < NB) ? s_cnt[t] : 0;
    if (t < 512) s_scan[t] = v;
    __syncthreads();
    for (int off = 1; off < 512; off <<= 1) {
        int add = (t < 512 && t >= off) ? s_scan[t - off] : 0;
        __syncthreads();
        if (t < 512) s_scan[t] += add;
        __syncthreads();
    }
    if (t < NB) {
        int ls = s_scan[t] - v;
        s_lstart[t] = ls;
        s_gbase[t] = (v > 0) ? atomicAdd(&bcur[t], v) : 0;
        s_cnt[t] = ls;
    }
    __syncthreads();

    for (int i = t; i < ecnt; i += 1024) {
        int d = dst[e0 + i];
        int s = src[e0 + i];
        int b = d >> 8;
        int slot = atomicAdd(&s_cnt[b], 1);
        s_val[slot]   = ((u32)(d & 255) << 17) | (u32)s;
        s_gaddr[slot] = (u32)(s_gbase[b] + (slot - s_lstart[b]));
    }
    __syncthreads();
    for (int i = t; i < ecnt; i += 1024)
        csrp[s_gaddr[i]] = s_val[i];
}

__global__ __launch_bounds__(1024) void p2_scatter(
    const int* __restrict__ bstart, int* __restrict__ rowstart,
    int* __restrict__ deg, int* __restrict__ csr)
{
    __shared__ u32 s_in[P2_CAP];
    __shared__ u32 s_out[P2_CAP];
    __shared__ int s_cnt[256];
    __shared__ int s_loc[256];
    const int b = blockIdx.x;
    const int t = threadIdx.x;
    const int n0 = b << 8;
    const int s0 = bstart[b];
    const int s1 = bstart[b + 1];
    const int cnt = s1 - s0;

    if (t < 256) s_cnt[t] = 0;
    __syncthreads();
    for (int i = t; i < cnt; i += 1024) {
        u32 p = (u32)csr[s0 + i];
        s_in[i] = p;
        atomicAdd(&s_cnt[p >> 17], 1);
    }
    __syncthreads();
    if (t < 256) s_loc[t] = s_cnt[t];
    __syncthreads();
    for (int off = 1; off < 256; off <<= 1) {
        int add = (t < 256 && t >= off) ? s_loc[t - off] : 0;
        __syncthreads();
        if (t < 256) s_loc[t] += add;
        __syncthreads();
    }
    if (t < 256) {
        int node = n0 + t;
        int excl = s_loc[t] - s_cnt[t];
        if (node < N_NODES) {
            rowstart[node] = s0 + excl;   // coalesced
            deg[node]      = s_cnt[t];    // coalesced
        }
        s_loc[t] = excl;
    }
    __syncthreads();
    for (int i = t; i < cnt; i += 1024) {
        u32 p = s_in[i];
        int pos = atomicAdd(&s_loc[p >> 17], 1);
        s_out[pos] = p & 0x1FFFFu;
    }
    __syncthreads();
    for (int i = t; i < cnt; i += 1024)
        csr[s0 + i] = (int)s_out[i];
}

// ---------------- casts ----------------

__global__ __launch_bounds__(256) void cast_x(const float* __restrict__ in,
                                              u16* __restrict__ out) {
    int i = blockIdx.x * 256 + threadIdx.x;   // 1.6M threads x 8 elems
    const float4 v0 = *(const float4*)(in + (size_t)i * 8);
    const float4 v1 = *(const float4*)(in + (size_t)i * 8 + 4);
    u16 o[8];
    o[0]=f2bf(v0.x); o[1]=f2bf(v0.y); o[2]=f2bf(v0.z); o[3]=f2bf(v0.w);
    o[4]=f2bf(v1.x); o[5]=f2bf(v1.y); o[6]=f2bf(v1.z); o[7]=f2bf(v1.w);
    *(bf16x8*)(out + (size_t)i * 8) = *(bf16x8*)o;
}

__global__ __launch_bounds__(256) void cast_w(const float* __restrict__ w1l,
                                              const float* __restrict__ w1r,
                                              const float* __restrict__ w2l,
                                              const float* __restrict__ w2r,
                                              u16* __restrict__ out) {
    int i = blockIdx.x * 256 + threadIdx.x;   // 65536 threads
    int mat = i >> 14, idx = i & 16383;
    const float* s = (mat == 0) ? w1l : (mat == 1) ? w1r : (mat == 2) ? w2l : w2r;
    out[i] = f2bf(s[idx]);
}

// ---------------- Aggregation v3: v1 layout (4B/lane, scalar idx loads), depth 16 ----------------
// R14 lesson: 16B/lane regressed (64.5 vs 60.5us) -- group-varying index loads
// lost the wave-uniform s_load dual-issue and concentrated unpack VALU. v3 =
// v1's layout (lane covers 2 cols; csr[beg+i+u] wave-uniform -> s_load) with
// MLP depth 16 (was 8): 16 independent row loads in flight per wave, 32 acc
// VGPRs. If this doesn't move, agg is at the random-gather path ceiling.
__global__ __launch_bounds__(256) void agg_bf16(
    const u16* __restrict__ xin, const int* __restrict__ csr,
    const int* __restrict__ rowstart, const int* __restrict__ deg,
    u16* __restrict__ mout)
{
    int w = (blockIdx.x * blockDim.x + threadIdx.x) >> 6;
    if (w >= N_NODES) return;
    int lane = threadIdx.x & 63;
    int beg = __builtin_amdgcn_readfirstlane(rowstart[w]);
    int d   = __builtin_amdgcn_readfirstlane(deg[w]);
    const u16* base = xin + (lane << 1);    // 2 bf16 (4B) per lane, row=256B

    float ax[16], ay[16];
#pragma unroll
    for (int u = 0; u < 16; ++u) { ax[u] = 0.f; ay[u] = 0.f; }

    int i = 0;
    for (; i + 16 <= d; i += 16) {
        int s[16];
#pragma unroll
        for (int u = 0; u < 16; ++u) s[u] = csr[beg + i + u];   // wave-uniform: s_load
#pragma unroll
        for (int u = 0; u < 16; ++u) {
            u32 v = *(const u32*)(base + ((size_t)s[u] << 7));
            ax[u] += __uint_as_float(v << 16);
            ay[u] += __uint_as_float(v & 0xffff0000u);
        }
    }
    if (i < d) {
        int cnt = d - i;  // 1..15, wave-uniform
        int s[16];
#pragma unroll
        for (int u = 0; u < 16; ++u) s[u] = csr[beg + i + ((u < cnt) ? u : 0)];
#pragma unroll
        for (int u = 0; u < 16; ++u) {
            u32 v = *(const u32*)(base + ((size_t)s[u] << 7));
            if (u < cnt) {   // wave-uniform predicate
                ax[u] += __uint_as_float(v << 16);
                ay[u] += __uint_as_float(v & 0xffff0000u);
            }
        }
    }

    // tree sum 16 -> 1
#pragma unroll
    for (int u = 0; u < 8; ++u) { ax[u] += ax[u + 8]; ay[u] += ay[u + 8]; }
#pragma unroll
    for (int u = 0; u < 4; ++u) { ax[u] += ax[u + 4]; ay[u] += ay[u + 4]; }
    ax[0] += ax[2]; ay[0] += ay[2];
    ax[1] += ax[3]; ay[1] += ay[3];
    ax[0] += ax[1]; ay[0] += ay[1];

    float inv = 1.f / (float)(d > 0 ? d : 1);
    u32 packed = (u32)f2bf(ax[0] * inv) | ((u32)f2bf(ay[0] * inv) << 16);
    *(u32*)(mout + ((size_t)w << 7) + (lane << 1)) = packed;
}

// ---------------- MFMA dual-GEMM v4: LDS bulk-stage + 1 barrier + coalesced out ----------------
__global__ __launch_bounds__(256) void gemm_mfma4(
    const u16* __restrict__ Ab, const u16* __restrict__ Xb,
    const u16* __restrict__ Wlb, const float* __restrict__ bl,
    const u16* __restrict__ Wrb, void* __restrict__ outp, int relu_bf16)
{
    __shared__ u16 lds[32768];          // 64KB: A[0,16384), X[16384,32768) u16 idx
    const int t  = threadIdx.x;
    const int wv = t >> 6;              // 0..3
    const int l  = t & 63;
    const int lr = l & 15;              // A-row / B-col / D-col in 16-tile
    const int lq = l >> 4;              // 0..3 k-slice / D-row group
    const int r0 = blockIdx.x * 128;

    // ---- weights: wave wv owns output cols [wv*32, wv*32+32) ----
    bf16x8 bwl[2][4], bwr[2][4];
#pragma unroll
    for (int ct = 0; ct < 2; ++ct) {
        const u16* wl = Wlb + (size_t)(wv * 32 + ct * 16 + lr) * H + lq * 8;
        const u16* wr = Wrb + (size_t)(wv * 32 + ct * 16 + lr) * H + lq * 8;
#pragma unroll
        for (int k0 = 0; k0 < 4; ++k0) {
            bwl[ct][k0] = *(const bf16x8*)(wl + k0 * 32);
            bwr[ct][k0] = *(const bf16x8*)(wr + k0 * 32);
        }
    }
    float bv[2] = { bl[wv * 32 + lr], bl[wv * 32 + 16 + lr] };

    // ---- bulk stage: each wave 8KB of A + 8KB of X, 1KB per inst ----
    const char* ag = (const char*)(Ab + (size_t)r0 * H);
    const char* xg = (const char*)(Xb + (size_t)r0 * H);
#pragma unroll
    for (int c = 0; c < 8; ++c) {
        int boff = wv * 8192 + c * 1024;          // wave-uniform byte offset
        __builtin_amdgcn_global_load_lds(
            (const u32*)(ag + boff + (l << 4)), (u32*)&lds[boff >> 1], 16, 0, 0);
        __builtin_amdgcn_global_load_lds(
            (const u32*)(xg + boff + (l << 4)), (u32*)&lds[(32768 + boff) >> 1], 16, 0, 0);
    }
    __syncthreads();   // drains staging vmcnt; tile visible to all waves

    // ---- compute: acc[rt][ct] fully in regs, static indexing ----
    f32x4 acc[8][2];
#pragma unroll
    for (int rt = 0; rt < 8; ++rt) {
        bf16x8 af[4], xf[4];
#pragma unroll
        for (int k0 = 0; k0 < 4; ++k0) {
            int idx = (rt * 16 + lr) * 128 + k0 * 32 + lq * 8;
            af[k0] = *(const bf16x8*)&lds[idx];
            xf[k0] = *(const bf16x8*)&lds[16384 + idx];
        }
#pragma unroll
        for (int ct = 0; ct < 2; ++ct) {
            f32x4 a = (f32x4)0.f;
#pragma unroll
            for (int k0 = 0; k0 < 4; ++k0) {
                a = __builtin_amdgcn_mfma_f32_16x16x32_bf16(af[k0], bwl[ct][k0], a, 0, 0, 0);
                a = __builtin_amdgcn_mfma_f32_16x16x32_bf16(xf[k0], bwr[ct][k0], a, 0, 0, 0);
            }
            acc[rt][ct] = a;
        }
    }
    __syncthreads();   // all LDS reads done; buffer reusable for out-tile

    // ---- epilogue: tile -> LDS, barrier, coalesced flush ----
    if (relu_bf16) {
#pragma unroll
        for (int rt = 0; rt < 8; ++rt)
#pragma unroll
        for (int ct = 0; ct < 2; ++ct)
#pragma unroll
        for (int r = 0; r < 4; ++r)
            lds[(rt * 16 + lq * 4 + r) * 128 + wv * 32 + ct * 16 + lr] =
                f2bf(fmaxf(acc[rt][ct][r] + bv[ct], 0.f));
        __syncthreads();
        u16* ob = (u16*)outp;
#pragma unroll
        for (int c = 0; c < 8; ++c) {
            int eoff = c * 2048 + t * 8;          // u16 elements
            int row = r0 + (eoff >> 7);
            if (row < N_NODES)
                *(bf16x8*)(ob + (size_t)r0 * H + eoff) = *(const bf16x8*)&lds[eoff];
        }
    } else {
        float* of = (float*)lds;
#pragma unroll
        for (int rt = 0; rt < 8; ++rt)
#pragma unroll
        for (int ct = 0; ct < 2; ++ct)
#pragma unroll
        for (int r = 0; r < 4; ++r)
            of[(rt * 16 + lq * 4 + r) * 128 + wv * 32 + ct * 16 + lr] =
                acc[rt][ct][r] + bv[ct];
        __syncthreads();
        float* og = (float*)outp;
#pragma unroll
        for (int c = 0; c < 16; ++c) {
            int eoff = c * 1024 + t * 4;          // f32 elements
            int row = r0 + (eoff >> 7);
            if (row < N_NODES)
                *(float4*)(og + (size_t)r0 * H + eoff) = *(const float4*)&of[eoff];
        }
    }
}

// ---------------- launch ----------------

extern "C" void kernel_launch(void* const* d_in, const int* in_sizes, int n_in,
                              void* d_out, int out_size, void* d_ws, size_t ws_size,
                              hipStream_t stream) {
    const float* x   = (const float*)d_in[0];
    const int*   ei  = (const int*)d_in[1];
    const float* W1l = (const float*)d_in[2];
    const float* b1l = (const float*)d_in[3];
    const float* W1r = (const float*)d_in[4];
    const float* W2l = (const float*)d_in[5];
    const float* b2l = (const float*)d_in[6];
    const float* W2r = (const float*)d_in[7];

    const int* src = ei;             // edge_index[0]
    const int* dst = ei + N_EDGES;   // edge_index[1]

    // workspace layout (~58.8 MB)
    u16* xb       = (u16*)d_ws;                          // N*H bf16; becomes h1b after gemm1
    u16* mb       = xb + (size_t)N_NODES * H;            // N*H bf16
    int* deg      = (int*)(mb + (size_t)N_NODES * H);    // N
    int* rowstart = deg + N_NODES;                       // N
    int* wslot    = rowstart + N_NODES;                  // N ints (bf16 weights home)
    int* csr      = wslot + N_NODES;                     // E
    int* gcount   = csr + N_EDGES;                       // NB
    int* bstart   = gcount + NB;                         // NB+1
    int* bcur     = bstart + NB + 1;                     // NB
    u16* Wb       = (u16*)wslot;                         // 4 x 128*128 bf16 = 128KB
    u16* W1lb = Wb;
    u16* W1rb = Wb + 16384;
    u16* W2lb = Wb + 32768;
    u16* W2rb = Wb + 49152;

    // CSR build: bucket histogram -> bucket scan -> 2-pass LDS counting sort
    zero_ints<<<(NB + 255) / 256, 256, 0, stream>>>(gcount, NB);
    bucket_count<<<P1_BLOCKS, 1024, 0, stream>>>(dst, gcount);
    bucket_scan<<<1, 512, 0, stream>>>(gcount, bstart, bcur);
    p1_bin<<<P1_BLOCKS, 1024, 0, stream>>>(src, dst, bcur, (u32*)csr);
    p2_scatter<<<NB, 1024, 0, stream>>>(bstart, rowstart, deg, csr);

    // precasts
    cast_w<<<65536 / 256, 256, 0, stream>>>(W1l, W1r, W2l, W2r, Wb);
    cast_x<<<(N_NODES * H / 8) / 256, 256, 0, stream>>>(x, xb);

    const int gemm_grid = (N_NODES + 127) / 128;   // 782

    // layer 1
    agg_bf16<<<(N_NODES + 3) / 4, 256, 0, stream>>>(xb, csr, rowstart, deg, mb);
    gemm_mfma4<<<gemm_grid, 256, 0, stream>>>(mb, xb, W1lb, b1l, W1rb, xb, 1);  // h1b in-place over xb

    // layer 2
    agg_bf16<<<(N_NODES + 3) / 4, 256, 0, stream>>>(xb, csr, rowstart, deg, mb);
    gemm_mfma4<<<gemm_grid, 256, 0, stream>>>(mb, xb, W2lb, b2l, W2rb, d_out, 0);
}

// Round 16
// 240.337 us; speedup vs baseline: 1.2663x; 1.2663x over previous
//
#include <hip/hip_runtime.h>

#define N_NODES 100000
#define N_EDGES 1600000
#define H 128

#define NB 391        // dst buckets of 256 nodes: ceil(100000/256)
#define P1_EPB 4096   // edges per pass-1/bucket-count block
#define P1_BLOCKS ((N_EDGES + P1_EPB - 1) / P1_EPB)   // 391
#define P2_CAP 6144   // bucket capacity (mean 4096, sigma~64)

typedef unsigned short u16;
typedef unsigned int u32;
typedef short bf16x8 __attribute__((ext_vector_type(8)));
typedef float f32x4 __attribute__((ext_vector_type(4)));

static __device__ __forceinline__ u16 f2bf(float f) {  // RNE float->bf16
    u32 u = __float_as_uint(f);
    u += 0x7fffu + ((u >> 16) & 1u);
    return (u16)(u >> 16);
}

// ---------------- CSR build ----------------
// R12 lesson: per-node random global atomics cost ~32B HBM writeback each.
// All per-node counting happens in LDS inside the bucketed counting sort.

__global__ void zero_ints(int* __restrict__ p, int n) {
    int i = blockIdx.x * blockDim.x + threadIdx.x;
    if (i < n) p[i] = 0;
}

__global__ __launch_bounds__(1024) void bucket_count(
    const int* __restrict__ dst, int* __restrict__ gcount)
{
    __shared__ int s_cnt[NB];
    const int t = threadIdx.x;
    const int e0 = blockIdx.x * P1_EPB;
    const int ecnt = min(P1_EPB, N_EDGES - e0);
    for (int i = t; i < NB; i += 1024) s_cnt[i] = 0;
    __syncthreads();
    for (int i = t; i < ecnt; i += 1024)
        atomicAdd(&s_cnt[dst[e0 + i] >> 8], 1);
    __syncthreads();
    for (int i = t; i < NB; i += 1024)
        if (s_cnt[i] > 0) atomicAdd(&gcount[i], s_cnt[i]);
}

__global__ __launch_bounds__(512) void bucket_scan(
    const int* __restrict__ gcount, int* __restrict__ bstart, int* __restrict__ bcur)
{
    __shared__ int s[512];
    int t = threadIdx.x;
    int v = (t < NB) ? gcount[t] : 0;
    s[t] = v;
    __syncthreads();
    for (int off = 1; off < 512; off <<= 1) {
        int add = (t >= off) ? s[t - off] : 0;
        __syncthreads();
        s[t] += add;
        __syncthreads();
    }
    if (t < NB) {
        int excl = s[t] - v;
        bstart[t] = excl;
        bcur[t] = excl;
    }
    if (t == NB - 1) bstart[NB] = s[t];   // == N_EDGES
}

__global__ __launch_bounds__(1024) void p1_bin(
    const int* __restrict__ src, const int* __restrict__ dst,
    int* __restrict__ bcur, u32* __restrict__ csrp)
{
    __shared__ int s_cnt[NB];      // histogram, then running local cursor
    __shared__ int s_lstart[NB];
    __shared__ int s_gbase[NB];
    __shared__ int s_scan[512];
    __shared__ u32 s_val[P1_EPB];
    __shared__ u32 s_gaddr[P1_EPB];

    const int t = threadIdx.x;
    const int e0 = blockIdx.x * P1_EPB;
    const int ecnt = min(P1_EPB, N_EDGES - e0);

    for (int i = t; i < NB; i += 1024) s_cnt[i] = 0;
    __syncthreads();
    for (int i = t; i < ecnt; i += 1024)
        atomicAdd(&s_cnt[dst[e0 + i] >> 8], 1);
    __syncthreads();

    int v = (t < NB) ? s_cnt[t] : 0;
    if (t < 512) s_scan[t] = v;
    __syncthreads();
    for (int off = 1; off < 512; off <<= 1) {
        int add = (t < 512 && t >= off) ? s_scan[t - off] : 0;
        __syncthreads();
        if (t < 512) s_scan[t] += add;
        __syncthreads();
    }
    if (t < NB) {
        int ls = s_scan[t] - v;
        s_lstart[t] = ls;
        s_gbase[t] = (v > 0) ? atomicAdd(&bcur[t], v) : 0;
        s_cnt[t] = ls;
    }
    __syncthreads();

    for (int i = t; i < ecnt; i += 1024) {
        int d = dst[e0 + i];
        int s = src[e0 + i];
        int b = d >> 8;
        int slot = atomicAdd(&s_cnt[b], 1);
        s_val[slot]   = ((u32)(d & 255) << 17) | (u32)s;
        s_gaddr[slot] = (u32)(s_gbase[b] + (slot - s_lstart[b]));
    }
    __syncthreads();
    for (int i = t; i < ecnt; i += 1024)
        csrp[s_gaddr[i]] = s_val[i];
}

__global__ __launch_bounds__(1024) void p2_scatter(
    const int* __restrict__ bstart, int* __restrict__ rowstart,
    int* __restrict__ deg, int* __restrict__ csr)
{
    __shared__ u32 s_in[P2_CAP];
    __shared__ u32 s_out[P2_CAP];
    __shared__ int s_cnt[256];
    __shared__ int s_loc[256];
    const int b = blockIdx.x;
    const int t = threadIdx.x;
    const int n0 = b << 8;
    const int s0 = bstart[b];
    const int s1 = bstart[b + 1];
    const int cnt = s1 - s0;

    if (t < 256) s_cnt[t] = 0;
    __syncthreads();
    for (int i = t; i < cnt; i += 1024) {
        u32 p = (u32)csr[s0 + i];
        s_in[i] = p;
        atomicAdd(&s_cnt[p >> 17], 1);
    }
    __syncthreads();
    if (t < 256) s_loc[t] = s_cnt[t];
    __syncthreads();
    for (int off = 1; off < 256; off <<= 1) {
        int add = (t < 256 && t >= off) ? s_loc[t - off] : 0;
        __syncthreads();
        if (t < 256) s_loc[t] += add;
        __syncthreads();
    }
    if (t < 256) {
        int node = n0 + t;
        int excl = s_loc[t] - s_cnt[t];
        if (node < N_NODES) {
            rowstart[node] = s0 + excl;   // coalesced
            deg[node]      = s_cnt[t];    // coalesced
        }
        s_loc[t] = excl;
    }
    __syncthreads();
    for (int i = t; i < cnt; i += 1024) {
        u32 p = s_in[i];
        int pos = atomicAdd(&s_loc[p >> 17], 1);
        s_out[pos] = p & 0x1FFFFu;
    }
    __syncthreads();
    for (int i = t; i < cnt; i += 1024)
        csr[s0 + i] = (int)s_out[i];
}

// ---------------- casts ----------------

__global__ __launch_bounds__(256) void cast_x(const float* __restrict__ in,
                                              u16* __restrict__ out) {
    int i = blockIdx.x * 256 + threadIdx.x;   // 1.6M threads x 8 elems
    const float4 v0 = *(const float4*)(in + (size_t)i * 8);
    const float4 v1 = *(const float4*)(in + (size_t)i * 8 + 4);
    u16 o[8];
    o[0]=f2bf(v0.x); o[1]=f2bf(v0.y); o[2]=f2bf(v0.z); o[3]=f2bf(v0.w);
    o[4]=f2bf(v1.x); o[5]=f2bf(v1.y); o[6]=f2bf(v1.z); o[7]=f2bf(v1.w);
    *(bf16x8*)(out + (size_t)i * 8) = *(bf16x8*)o;
}

__global__ __launch_bounds__(256) void cast_w(const float* __restrict__ w1l,
                                              const float* __restrict__ w1r,
                                              const float* __restrict__ w2l,
                                              const float* __restrict__ w2r,
                                              u16* __restrict__ out) {
    int i = blockIdx.x * 256 + threadIdx.x;   // 65536 threads
    int mat = i >> 14, idx = i & 16383;
    const float* s = (mat == 0) ? w1l : (mat == 1) ? w1r : (mat == 2) ? w2l : w2r;
    out[i] = f2bf(s[idx]);
}

// ---------------- Aggregation (R13 v1, PROVEN best): wave/node, depth-8 MLP ----------------
// R14 (16B/lane: 64.5us) and R15 (depth-16: 94.7us, occupancy 70->52%) both
// regressed vs this version's 60.5us. Arithmetic: 410MB logical row reads /
// 60.5us = 6.8 TB/s combined L2/L3 service -- at the random-256B-gather
// bandwidth ceiling; queue depth is not binding. This structure is final.
__global__ __launch_bounds__(256) void agg_bf16(
    const u16* __restrict__ xin, const int* __restrict__ csr,
    const int* __restrict__ rowstart, const int* __restrict__ deg,
    u16* __restrict__ mout)
{
    int w = (blockIdx.x * blockDim.x + threadIdx.x) >> 6;
    if (w >= N_NODES) return;
    int lane = threadIdx.x & 63;
    int beg = __builtin_amdgcn_readfirstlane(rowstart[w]);
    int d   = __builtin_amdgcn_readfirstlane(deg[w]);
    const u16* base = xin + (lane << 1);    // 2 bf16 (4B) per lane, row=256B

    float ax[8], ay[8];
#pragma unroll
    for (int u = 0; u < 8; ++u) { ax[u] = 0.f; ay[u] = 0.f; }

    int i = 0;
    for (; i + 8 <= d; i += 8) {
        int s[8];
#pragma unroll
        for (int u = 0; u < 8; ++u) s[u] = csr[beg + i + u];   // wave-uniform: s_load
#pragma unroll
        for (int u = 0; u < 8; ++u) {
            u32 v = *(const u32*)(base + ((size_t)s[u] << 7));
            ax[u] += __uint_as_float(v << 16);
            ay[u] += __uint_as_float(v & 0xffff0000u);
        }
    }
    if (i < d) {
        int cnt = d - i;  // 1..7, wave-uniform
        int s[8];
#pragma unroll
        for (int u = 0; u < 8; ++u) s[u] = csr[beg + i + ((u < cnt) ? u : 0)];
#pragma unroll
        for (int u = 0; u < 8; ++u) {
            u32 v = *(const u32*)(base + ((size_t)s[u] << 7));
            if (u < cnt) {
                ax[u] += __uint_as_float(v << 16);
                ay[u] += __uint_as_float(v & 0xffff0000u);
            }
        }
    }

#pragma unroll
    for (int u = 0; u < 4; ++u) { ax[u] += ax[u + 4]; ay[u] += ay[u + 4]; }
    ax[0] += ax[2]; ay[0] += ay[2];
    ax[1] += ax[3]; ay[1] += ay[3];
    ax[0] += ax[1]; ay[0] += ay[1];

    float inv = 1.f / (float)(d > 0 ? d : 1);
    u32 packed = (u32)f2bf(ax[0] * inv) | ((u32)f2bf(ay[0] * inv) << 16);
    *(u32*)(mout + ((size_t)w << 7) + (lane << 1)) = packed;
}

// ---------------- MFMA dual-GEMM v4: LDS bulk-stage + 1 barrier + coalesced out ----------------
__global__ __launch_bounds__(256) void gemm_mfma4(
    const u16* __restrict__ Ab, const u16* __restrict__ Xb,
    const u16* __restrict__ Wlb, const float* __restrict__ bl,
    const u16* __restrict__ Wrb, void* __restrict__ outp, int relu_bf16)
{
    __shared__ u16 lds[32768];          // 64KB: A[0,16384), X[16384,32768) u16 idx
    const int t  = threadIdx.x;
    const int wv = t >> 6;              // 0..3
    const int l  = t & 63;
    const int lr = l & 15;              // A-row / B-col / D-col in 16-tile
    const int lq = l >> 4;              // 0..3 k-slice / D-row group
    const int r0 = blockIdx.x * 128;

    // ---- weights: wave wv owns output cols [wv*32, wv*32+32) ----
    bf16x8 bwl[2][4], bwr[2][4];
#pragma unroll
    for (int ct = 0; ct < 2; ++ct) {
        const u16* wl = Wlb + (size_t)(wv * 32 + ct * 16 + lr) * H + lq * 8;
        const u16* wr = Wrb + (size_t)(wv * 32 + ct * 16 + lr) * H + lq * 8;
#pragma unroll
        for (int k0 = 0; k0 < 4; ++k0) {
            bwl[ct][k0] = *(const bf16x8*)(wl + k0 * 32);
            bwr[ct][k0] = *(const bf16x8*)(wr + k0 * 32);
        }
    }
    float bv[2] = { bl[wv * 32 + lr], bl[wv * 32 + 16 + lr] };

    // ---- bulk stage: each wave 8KB of A + 8KB of X, 1KB per inst ----
    const char* ag = (const char*)(Ab + (size_t)r0 * H);
    const char* xg = (const char*)(Xb + (size_t)r0 * H);
#pragma unroll
    for (int c = 0; c < 8; ++c) {
        int boff = wv * 8192 + c * 1024;          // wave-uniform byte offset
        __builtin_amdgcn_global_load_lds(
            (const u32*)(ag + boff + (l << 4)), (u32*)&lds[boff >> 1], 16, 0, 0);
        __builtin_amdgcn_global_load_lds(
            (const u32*)(xg + boff + (l << 4)), (u32*)&lds[(32768 + boff) >> 1], 16, 0, 0);
    }
    __syncthreads();   // drains staging vmcnt; tile visible to all waves

    // ---- compute: acc[rt][ct] fully in regs, static indexing ----
    f32x4 acc[8][2];
#pragma unroll
    for (int rt = 0; rt < 8; ++rt) {
        bf16x8 af[4], xf[4];
#pragma unroll
        for (int k0 = 0; k0 < 4; ++k0) {
            int idx = (rt * 16 + lr) * 128 + k0 * 32 + lq * 8;
            af[k0] = *(const bf16x8*)&lds[idx];
            xf[k0] = *(const bf16x8*)&lds[16384 + idx];
        }
#pragma unroll
        for (int ct = 0; ct < 2; ++ct) {
            f32x4 a = (f32x4)0.f;
#pragma unroll
            for (int k0 = 0; k0 < 4; ++k0) {
                a = __builtin_amdgcn_mfma_f32_16x16x32_bf16(af[k0], bwl[ct][k0], a, 0, 0, 0);
                a = __builtin_amdgcn_mfma_f32_16x16x32_bf16(xf[k0], bwr[ct][k0], a, 0, 0, 0);
            }
            acc[rt][ct] = a;
        }
    }
    __syncthreads();   // all LDS reads done; buffer reusable for out-tile

    // ---- epilogue: tile -> LDS, barrier, coalesced flush ----
    if (relu_bf16) {
#pragma unroll
        for (int rt = 0; rt < 8; ++rt)
#pragma unroll
        for (int ct = 0; ct < 2; ++ct)
#pragma unroll
        for (int r = 0; r < 4; ++r)
            lds[(rt * 16 + lq * 4 + r) * 128 + wv * 32 + ct * 16 + lr] =
                f2bf(fmaxf(acc[rt][ct][r] + bv[ct], 0.f));
        __syncthreads();
        u16* ob = (u16*)outp;
#pragma unroll
        for (int c = 0; c < 8; ++c) {
            int eoff = c * 2048 + t * 8;          // u16 elements
            int row = r0 + (eoff >> 7);
            if (row < N_NODES)
                *(bf16x8*)(ob + (size_t)r0 * H + eoff) = *(const bf16x8*)&lds[eoff];
        }
    } else {
        float* of = (float*)lds;
#pragma unroll
        for (int rt = 0; rt < 8; ++rt)
#pragma unroll
        for (int ct = 0; ct < 2; ++ct)
#pragma unroll
        for (int r = 0; r < 4; ++r)
            of[(rt * 16 + lq * 4 + r) * 128 + wv * 32 + ct * 16 + lr] =
                acc[rt][ct][r] + bv[ct];
        __syncthreads();
        float* og = (float*)outp;
#pragma unroll
        for (int c = 0; c < 16; ++c) {
            int eoff = c * 1024 + t * 4;          // f32 elements
            int row = r0 + (eoff >> 7);
            if (row < N_NODES)
                *(float4*)(og + (size_t)r0 * H + eoff) = *(const float4*)&of[eoff];
        }
    }
}

// ---------------- launch ----------------

extern "C" void kernel_launch(void* const* d_in, const int* in_sizes, int n_in,
                              void* d_out, int out_size, void* d_ws, size_t ws_size,
                              hipStream_t stream) {
    const float* x   = (const float*)d_in[0];
    const int*   ei  = (const int*)d_in[1];
    const float* W1l = (const float*)d_in[2];
    const float* b1l = (const float*)d_in[3];
    const float* W1r = (const float*)d_in[4];
    const float* W2l = (const float*)d_in[5];
    const float* b2l = (const float*)d_in[6];
    const float* W2r = (const float*)d_in[7];

    const int* src = ei;             // edge_index[0]
    const int* dst = ei + N_EDGES;   // edge_index[1]

    // workspace layout (~58.8 MB)
    u16* xb       = (u16*)d_ws;                          // N*H bf16; becomes h1b after gemm1
    u16* mb       = xb + (size_t)N_NODES * H;            // N*H bf16
    int* deg      = (int*)(mb + (size_t)N_NODES * H);    // N
    int* rowstart = deg + N_NODES;                       // N
    int* wslot    = rowstart + N_NODES;                  // N ints (bf16 weights home)
    int* csr      = wslot + N_NODES;                     // E
    int* gcount   = csr + N_EDGES;                       // NB
    int* bstart   = gcount + NB;                         // NB+1
    int* bcur     = bstart + NB + 1;                     // NB
    u16* Wb       = (u16*)wslot;                         // 4 x 128*128 bf16 = 128KB
    u16* W1lb = Wb;
    u16* W1rb = Wb + 16384;
    u16* W2lb = Wb + 32768;
    u16* W2rb = Wb + 49152;

    // CSR build: bucket histogram -> bucket scan -> 2-pass LDS counting sort
    zero_ints<<<(NB + 255) / 256, 256, 0, stream>>>(gcount, NB);
    bucket_count<<<P1_BLOCKS, 1024, 0, stream>>>(dst, gcount);
    bucket_scan<<<1, 512, 0, stream>>>(gcount, bstart, bcur);
    p1_bin<<<P1_BLOCKS, 1024, 0, stream>>>(src, dst, bcur, (u32*)csr);
    p2_scatter<<<NB, 1024, 0, stream>>>(bstart, rowstart, deg, csr);

    // precasts
    cast_w<<<65536 / 256, 256, 0, stream>>>(W1l, W1r, W2l, W2r, Wb);
    cast_x<<<(N_NODES * H / 8) / 256, 256, 0, stream>>>(x, xb);

    const int gemm_grid = (N_NODES + 127) / 128;   // 782

    // layer 1
    agg_bf16<<<(N_NODES + 3) / 4, 256, 0, stream>>>(xb, csr, rowstart, deg, mb);
    gemm_mfma4<<<gemm_grid, 256, 0, stream>>>(mb, xb, W1lb, b1l, W1rb, xb, 1);  // h1b in-place over xb

    // layer 2
    agg_bf16<<<(N_NODES + 3) / 4, 256, 0, stream>>>(xb, csr, rowstart, deg, mb);
    gemm_mfma4<<<gemm_grid, 256, 0, stream>>>(mb, xb, W2lb, b2l, W2rb, d_out, 0);
}

// Round 18
// 230.621 us; speedup vs baseline: 1.3196x; 1.0421x over previous
//
#include <hip/hip_runtime.h>

#define N_NODES 100000
#define N_EDGES 1600000
#define H 128

#define NB 391        // dst buckets of 256 nodes: ceil(100000/256)
#define P1_EPB 4096   // edges per pass-1 block
#define P1_BLOCKS ((N_EDGES + P1_EPB - 1) / P1_EPB)   // 391
#define P2_CAP 6144   // bucket capacity (mean 4092, sigma~64; +32 sigma)

typedef unsigned short u16;
typedef unsigned int u32;
typedef short bf16x8 __attribute__((ext_vector_type(8)));
typedef float f32x4 __attribute__((ext_vector_type(4)));

static __device__ __forceinline__ u16 f2bf(float f) {  // RNE float->bf16
    u32 u = __float_as_uint(f);
    u += 0x7fffu + ((u >> 16) & 1u);
    return (u16)(u >> 16);
}

// ---------------- CSR build ----------------
// R12 lesson: per-node random global atomics cost ~32B HBM writeback each.
// R16->R17: bucket_count deleted -- p1 reserves into a capacity-padded staging
// area (bucket b owns [b*P2_CAP, ...)) so no pre-scan of totals is needed;
// bcur's post-p1 values ARE the totals, scanned afterward for the compact csr.

__global__ void zero_ints(int* __restrict__ p, int n) {
    int i = blockIdx.x * blockDim.x + threadIdx.x;
    if (i < n) p[i] = 0;
}

// Pass 1: bin edges by dst>>8 into padded per-bucket staging (packed u32:
// bits[24:17]=dst&255, bits[16:0]=src). LDS-staged so global writes are
// slot-ordered bucket runs (R6/R7: raw 4B scatter = 64B partial-line HBM
// writebacks; XCD L2s can't merge).
__global__ __launch_bounds__(1024) void p1_bin(
    const int* __restrict__ src, const int* __restrict__ dst,
    int* __restrict__ bcur, u32* __restrict__ stage)
{
    __shared__ int s_cnt[NB];      // histogram, then running local cursor
    __shared__ int s_lstart[NB];
    __shared__ int s_gbase[NB];    // reserved slot base within bucket's pad
    __shared__ int s_scan[512];
    __shared__ u32 s_val[P1_EPB];
    __shared__ u32 s_gaddr[P1_EPB];

    const int t = threadIdx.x;
    const int e0 = blockIdx.x * P1_EPB;
    const int ecnt = min(P1_EPB, N_EDGES - e0);

    for (int i = t; i < NB; i += 1024) s_cnt[i] = 0;
    __syncthreads();
    for (int i = t; i < ecnt; i += 1024)
        atomicAdd(&s_cnt[dst[e0 + i] >> 8], 1);
    __syncthreads();

    int v = (t < NB) ? s_cnt[t] : 0;
    if (t < 512) s_scan[t] = v;
    __syncthreads();
    for (int off = 1; off < 512; off <<= 1) {
        int add = (t < 512 && t >= off) ? s_scan[t - off] : 0;
        __syncthreads();
        if (t < 512) s_scan[t] += add;
        __syncthreads();
    }
    if (t < NB) {
        int ls = s_scan[t] - v;
        s_lstart[t] = ls;
        s_gbase[t] = (v > 0) ? atomicAdd(&bcur[t], v) : 0;   // bcur starts at 0
        s_cnt[t] = ls;
    }
    __syncthreads();

    for (int i = t; i < ecnt; i += 1024) {
        int d = dst[e0 + i];
        int s = src[e0 + i];
        int b = d >> 8;
        int slot = atomicAdd(&s_cnt[b], 1);
        s_val[slot]   = ((u32)(d & 255) << 17) | (u32)s;
        s_gaddr[slot] = (u32)(b * P2_CAP + s_gbase[b] + (slot - s_lstart[b]));
    }
    __syncthreads();
    for (int i = t; i < ecnt; i += 1024)
        stage[s_gaddr[i]] = s_val[i];
}

// scan the post-p1 bcur totals -> bstart (exclusive, +sentinel)
__global__ __launch_bounds__(512) void bucket_scan(
    const int* __restrict__ bcur, int* __restrict__ bstart)
{
    __shared__ int s[512];
    int t = threadIdx.x;
    int v = (t < NB) ? bcur[t] : 0;
    s[t] = v;
    __syncthreads();
    for (int off = 1; off < 512; off <<= 1) {
        int add = (t >= off) ? s[t - off] : 0;
        __syncthreads();
        s[t] += add;
        __syncthreads();
    }
    if (t < NB) bstart[t] = s[t] - v;
    if (t == NB - 1) bstart[NB] = s[t];   // == N_EDGES
}

// Pass 2: one block per bucket. Reads padded staging; LDS-histograms the 256
// dst-lows -> scan -> deg/rowstart written COALESCED; in-LDS node-order
// scatter; compact csr written coalesced at bstart[b].
__global__ __launch_bounds__(1024) void p2_scatter(
    const int* __restrict__ bstart, const u32* __restrict__ stage,
    int* __restrict__ rowstart, int* __restrict__ deg, int* __restrict__ csr)
{
    __shared__ u32 s_in[P2_CAP];
    __shared__ u32 s_out[P2_CAP];
    __shared__ int s_cnt[256];
    __shared__ int s_loc[256];
    const int b = blockIdx.x;
    const int t = threadIdx.x;
    const int n0 = b << 8;
    const int s0 = bstart[b];
    const int cnt = bstart[b + 1] - s0;
    const u32* sb = stage + (size_t)b * P2_CAP;

    if (t < 256) s_cnt[t] = 0;
    __syncthreads();
    for (int i = t; i < cnt; i += 1024) {
        u32 p = sb[i];
        s_in[i] = p;
        atomicAdd(&s_cnt[p >> 17], 1);
    }
    __syncthreads();
    if (t < 256) s_loc[t] = s_cnt[t];
    __syncthreads();
    for (int off = 1; off < 256; off <<= 1) {
        int add = (t < 256 && t >= off) ? s_loc[t - off] : 0;
        __syncthreads();
        if (t < 256) s_loc[t] += add;
        __syncthreads();
    }
    if (t < 256) {
        int node = n0 + t;
        int excl = s_loc[t] - s_cnt[t];
        if (node < N_NODES) {
            rowstart[node] = s0 + excl;   // coalesced
            deg[node]      = s_cnt[t];    // coalesced
        }
        s_loc[t] = excl;
    }
    __syncthreads();
    for (int i = t; i < cnt; i += 1024) {
        u32 p = s_in[i];
        int pos = atomicAdd(&s_loc[p >> 17], 1);
        s_out[pos] = p & 0x1FFFFu;
    }
    __syncthreads();
    for (int i = t; i < cnt; i += 1024)
        csr[s0 + i] = (int)s_out[i];
}

// ---------------- casts ----------------

__global__ __launch_bounds__(256) void cast_x(const float* __restrict__ in,
                                              u16* __restrict__ out) {
    int i = blockIdx.x * 256 + threadIdx.x;   // 1.6M threads x 8 elems
    const float4 v0 = *(const float4*)(in + (size_t)i * 8);
    const float4 v1 = *(const float4*)(in + (size_t)i * 8 + 4);
    u16 o[8];
    o[0]=f2bf(v0.x); o[1]=f2bf(v0.y); o[2]=f2bf(v0.z); o[3]=f2bf(v0.w);
    o[4]=f2bf(v1.x); o[5]=f2bf(v1.y); o[6]=f2bf(v1.z); o[7]=f2bf(v1.w);
    *(bf16x8*)(out + (size_t)i * 8) = *(bf16x8*)o;
}

__global__ __launch_bounds__(256) void cast_w(const float* __restrict__ w1l,
                                              const float* __restrict__ w1r,
                                              const float* __restrict__ w2l,
                                              const float* __restrict__ w2r,
                                              u16* __restrict__ out) {
    int i = blockIdx.x * 256 + threadIdx.x;   // 65536 threads
    int mat = i >> 14, idx = i & 16383;
    const float* s = (mat == 0) ? w1l : (mat == 1) ? w1r : (mat == 2) ? w2l : w2r;
    out[i] = f2bf(s[idx]);
}

// ---------------- Aggregation (R13 v1, PROVEN best): wave/node, depth-8 MLP ----------------
// R14 (16B/lane) and R15 (depth-16) both regressed vs this 60.5us version.
// 410MB logical reads / 60.5us = 6.8 TB/s L2+L3 service -- at the
// random-256B-gather ceiling. This structure is final.
__global__ __launch_bounds__(256) void agg_bf16(
    const u16* __restrict__ xin, const int* __restrict__ csr,
    const int* __restrict__ rowstart, const int* __restrict__ deg,
    u16* __restrict__ mout)
{
    int w = (blockIdx.x * blockDim.x + threadIdx.x) >> 6;
    if (w >= N_NODES) return;
    int lane = threadIdx.x & 63;
    int beg = __builtin_amdgcn_readfirstlane(rowstart[w]);
    int d   = __builtin_amdgcn_readfirstlane(deg[w]);
    const u16* base = xin + (lane << 1);    // 2 bf16 (4B) per lane, row=256B

    float ax[8], ay[8];
#pragma unroll
    for (int u = 0; u < 8; ++u) { ax[u] = 0.f; ay[u] = 0.f; }

    int i = 0;
    for (; i + 8 <= d; i += 8) {
        int s[8];
#pragma unroll
        for (int u = 0; u < 8; ++u) s[u] = csr[beg + i + u];   // wave-uniform: s_load
#pragma unroll
        for (int u = 0; u < 8; ++u) {
            u32 v = *(const u32*)(base + ((size_t)s[u] << 7));
            ax[u] += __uint_as_float(v << 16);
            ay[u] += __uint_as_float(v & 0xffff0000u);
        }
    }
    if (i < d) {
        int cnt = d - i;  // 1..7, wave-uniform
        int s[8];
#pragma unroll
        for (int u = 0; u < 8; ++u) s[u] = csr[beg + i + ((u < cnt) ? u : 0)];
#pragma unroll
        for (int u = 0; u < 8; ++u) {
            u32 v = *(const u32*)(base + ((size_t)s[u] << 7));
            if (u < cnt) {
                ax[u] += __uint_as_float(v << 16);
                ay[u] += __uint_as_float(v & 0xffff0000u);
            }
        }
    }

#pragma unroll
    for (int u = 0; u < 4; ++u) { ax[u] += ax[u + 4]; ay[u] += ay[u + 4]; }
    ax[0] += ax[2]; ay[0] += ay[2];
    ax[1] += ax[3]; ay[1] += ay[3];
    ax[0] += ax[1]; ay[0] += ay[1];

    float inv = 1.f / (float)(d > 0 ? d : 1);
    u32 packed = (u32)f2bf(ax[0] * inv) | ((u32)f2bf(ay[0] * inv) << 16);
    *(u32*)(mout + ((size_t)w << 7) + (lane << 1)) = packed;
}

// ---------------- MFMA dual-GEMM v4: LDS bulk-stage + 1 barrier + coalesced out ----------------
__global__ __launch_bounds__(256) void gemm_mfma4(
    const u16* __restrict__ Ab, const u16* __restrict__ Xb,
    const u16* __restrict__ Wlb, const float* __restrict__ bl,
    const u16* __restrict__ Wrb, void* __restrict__ outp, int relu_bf16)
{
    __shared__ u16 lds[32768];          // 64KB: A[0,16384), X[16384,32768) u16 idx
    const int t  = threadIdx.x;
    const int wv = t >> 6;              // 0..3
    const int l  = t & 63;
    const int lr = l & 15;              // A-row / B-col / D-col in 16-tile
    const int lq = l >> 4;              // 0..3 k-slice / D-row group
    const int r0 = blockIdx.x * 128;

    // ---- weights: wave wv owns output cols [wv*32, wv*32+32) ----
    bf16x8 bwl[2][4], bwr[2][4];
#pragma unroll
    for (int ct = 0; ct < 2; ++ct) {
        const u16* wl = Wlb + (size_t)(wv * 32 + ct * 16 + lr) * H + lq * 8;
        const u16* wr = Wrb + (size_t)(wv * 32 + ct * 16 + lr) * H + lq * 8;
#pragma unroll
        for (int k0 = 0; k0 < 4; ++k0) {
            bwl[ct][k0] = *(const bf16x8*)(wl + k0 * 32);
            bwr[ct][k0] = *(const bf16x8*)(wr + k0 * 32);
        }
    }
    float bv[2] = { bl[wv * 32 + lr], bl[wv * 32 + 16 + lr] };

    // ---- bulk stage: each wave 8KB of A + 8KB of X, 1KB per inst ----
    const char* ag = (const char*)(Ab + (size_t)r0 * H);
    const char* xg = (const char*)(Xb + (size_t)r0 * H);
#pragma unroll
    for (int c = 0; c < 8; ++c) {
        int boff = wv * 8192 + c * 1024;          // wave-uniform byte offset
        __builtin_amdgcn_global_load_lds(
            (const u32*)(ag + boff + (l << 4)), (u32*)&lds[boff >> 1], 16, 0, 0);
        __builtin_amdgcn_global_load_lds(
            (const u32*)(xg + boff + (l << 4)), (u32*)&lds[(32768 + boff) >> 1], 16, 0, 0);
    }
    __syncthreads();   // drains staging vmcnt; tile visible to all waves

    // ---- compute: acc[rt][ct] fully in regs, static indexing ----
    f32x4 acc[8][2];
#pragma unroll
    for (int rt = 0; rt < 8; ++rt) {
        bf16x8 af[4], xf[4];
#pragma unroll
        for (int k0 = 0; k0 < 4; ++k0) {
            int idx = (rt * 16 + lr) * 128 + k0 * 32 + lq * 8;
            af[k0] = *(const bf16x8*)&lds[idx];
            xf[k0] = *(const bf16x8*)&lds[16384 + idx];
        }
#pragma unroll
        for (int ct = 0; ct < 2; ++ct) {
            f32x4 a = (f32x4)0.f;
#pragma unroll
            for (int k0 = 0; k0 < 4; ++k0) {
                a = __builtin_amdgcn_mfma_f32_16x16x32_bf16(af[k0], bwl[ct][k0], a, 0, 0, 0);
                a = __builtin_amdgcn_mfma_f32_16x16x32_bf16(xf[k0], bwr[ct][k0], a, 0, 0, 0);
            }
            acc[rt][ct] = a;
        }
    }
    __syncthreads();   // all LDS reads done; buffer reusable for out-tile

    // ---- epilogue: tile -> LDS, barrier, coalesced flush ----
    if (relu_bf16) {
#pragma unroll
        for (int rt = 0; rt < 8; ++rt)
#pragma unroll
        for (int ct = 0; ct < 2; ++ct)
#pragma unroll
        for (int r = 0; r < 4; ++r)
            lds[(rt * 16 + lq * 4 + r) * 128 + wv * 32 + ct * 16 + lr] =
                f2bf(fmaxf(acc[rt][ct][r] + bv[ct], 0.f));
        __syncthreads();
        u16* ob = (u16*)outp;
#pragma unroll
        for (int c = 0; c < 8; ++c) {
            int eoff = c * 2048 + t * 8;          // u16 elements
            int row = r0 + (eoff >> 7);
            if (row < N_NODES)
                *(bf16x8*)(ob + (size_t)r0 * H + eoff) = *(const bf16x8*)&lds[eoff];
        }
    } else {
        float* of = (float*)lds;
#pragma unroll
        for (int rt = 0; rt < 8; ++rt)
#pragma unroll
        for (int ct = 0; ct < 2; ++ct)
#pragma unroll
        for (int r = 0; r < 4; ++r)
            of[(rt * 16 + lq * 4 + r) * 128 + wv * 32 + ct * 16 + lr] =
                acc[rt][ct][r] + bv[ct];
        __syncthreads();
        float* og = (float*)outp;
#pragma unroll
        for (int c = 0; c < 16; ++c) {
            int eoff = c * 1024 + t * 4;          // f32 elements
            int row = r0 + (eoff >> 7);
            if (row < N_NODES)
                *(float4*)(og + (size_t)r0 * H + eoff) = *(const float4*)&of[eoff];
        }
    }
}

// ---------------- launch ----------------

extern "C" void kernel_launch(void* const* d_in, const int* in_sizes, int n_in,
                              void* d_out, int out_size, void* d_ws, size_t ws_size,
                              hipStream_t stream) {
    const float* x   = (const float*)d_in[0];
    const int*   ei  = (const int*)d_in[1];
    const float* W1l = (const float*)d_in[2];
    const float* b1l = (const float*)d_in[3];
    const float* W1r = (const float*)d_in[4];
    const float* W2l = (const float*)d_in[5];
    const float* b2l = (const float*)d_in[6];
    const float* W2r = (const float*)d_in[7];

    const int* src = ei;             // edge_index[0]
    const int* dst = ei + N_EDGES;   // edge_index[1]

    // workspace layout (~58.8 MB)
    u16* xb       = (u16*)d_ws;                          // N*H bf16; becomes h1b after gemm1
    u16* mb       = xb + (size_t)N_NODES * H;            // N*H bf16; ALSO hosts the 9.6MB
                                                         // padded CSR staging (dead until agg1)
    int* deg      = (int*)(mb + (size_t)N_NODES * H);    // N
    int* rowstart = deg + N_NODES;                       // N
    int* wslot    = rowstart + N_NODES;                  // N ints (bf16 weights home)
    int* csr      = wslot + N_NODES;                     // E
    int* bstart   = csr + N_EDGES;                       // NB+1
    int* bcur     = bstart + NB + 1;                     // NB
    u32* stage    = (u32*)mb;                            // NB * P2_CAP u32 = 9.6MB (< 25.6MB)
    u16* Wb       = (u16*)wslot;                         // 4 x 128*128 bf16 = 128KB
    u16* W1lb = Wb;
    u16* W1rb = Wb + 16384;
    u16* W2lb = Wb + 32768;
    u16* W2rb = Wb + 49152;

    // CSR build: padded-staging counting sort (bucket_count kernel deleted:
    // p1 reserves directly; bcur's post-p1 totals are scanned into bstart)
    zero_ints<<<(NB + 255) / 256, 256, 0, stream>>>(bcur, NB);
    p1_bin<<<P1_BLOCKS, 1024, 0, stream>>>(src, dst, bcur, stage);
    bucket_scan<<<1, 512, 0, stream>>>(bcur, bstart);
    p2_scatter<<<NB, 1024, 0, stream>>>(bstart, stage, rowstart, deg, csr);

    // precasts
    cast_w<<<65536 / 256, 256, 0, stream>>>(W1l, W1r, W2l, W2r, Wb);
    cast_x<<<(N_NODES * H / 8) / 256, 256, 0, stream>>>(x, xb);

    const int gemm_grid = (N_NODES + 127) / 128;   // 782

    // layer 1 (agg overwrites mb -> staging is dead by now)
    agg_bf16<<<(N_NODES + 3) / 4, 256, 0, stream>>>(xb, csr, rowstart, deg, mb);
    gemm_mfma4<<<gemm_grid, 256, 0, stream>>>(mb, xb, W1lb, b1l, W1rb, xb, 1);  // h1b in-place over xb

    // layer 2
    agg_bf16<<<(N_NODES + 3) / 4, 256, 0, stream>>>(xb, csr, rowstart, deg, mb);
    gemm_mfma4<<<gemm_grid, 256, 0, stream>>>(mb, xb, W2lb, b2l, W2rb, d_out, 0);
}